// Round 11
// baseline (352.477 us; speedup 1.0000x reference)
//
#include <hip/hip_runtime.h>
#include <math.h>

typedef __bf16 bf16x8 __attribute__((ext_vector_type(8)));
typedef float  f32x4  __attribute__((ext_vector_type(4)));
// may_alias views for the unioned LDS region (state-frags <-> per-wave zbuf)
typedef bf16x8 bf16x8_a __attribute__((may_alias));
typedef f32x4  f32x4_a  __attribute__((may_alias));
typedef float  f32_a    __attribute__((may_alias));

#define MSAMP 6       // samples per block; state-rows: r = s*6 + m, rows 42..47 pad

__device__ __forceinline__ float tanh_fast(float x) {
    // 1 - 2/(exp(2x)+1); ~1e-6 abs error (verified R7..R10: absmax unchanged)
    const float e = __expf(2.0f * x);
    return 1.0f - 2.0f * __builtin_amdgcn_rcpf(e + 1.0f);
}

// W swizzle (bf16 elems) — UNCHANGED from R2..R10: off(l,kt,jt,split,lane,jj) =
//   (((l*8+kt)*16+jt)*2+split)*512 + lane*8 + jj ; per-l stride 131072 elems
// A-fragments of W^T: lane holds A[j = jt*16+(lane&15)][k = kt*32+(lane>>4)*8+jj]
__global__ void prep_w(const float* __restrict__ W1, const float* __restrict__ W2,
                       const float* __restrict__ W3, __bf16* __restrict__ wsw) {
    const int tid = blockIdx.x * 256 + threadIdx.x;      // 3*8*16*64*8 = 196608
    if (tid >= 3 * 8 * 16 * 64 * 8) return;
    const int j    = tid & 7;
    const int lane = (tid >> 3) & 63;
    const int nt   = (tid >> 9) & 15;
    const int kt   = (tid >> 13) & 7;
    const int l    = tid >> 16;
    const float* W = (l == 0) ? W1 : (l == 1) ? W2 : W3;
    const int k = kt * 32 + (lane >> 4) * 8 + j;
    const int n = nt * 16 + (lane & 15);
    const float w = W[k * 256 + n];
    const __bf16 hi = (__bf16)w;
    const __bf16 lo = (__bf16)(w - (float)hi);
    const size_t base = ((size_t)((l * 8 + kt) * 16 + nt) * 2) * 512 + lane * 8 + j;
    wsw[base]       = hi;
    wsw[base + 512] = lo;
}

// TRANSPOSED GEMM, M=48 tile: D[j][r] = sum_k W^T[j][k]*S^T[k][r], 3 rt tiles.
// State B-frags: Bhi (24576 B) | Blo (24576 B), vec idx = (kt*3 + rt)*64 + lane.
// Wave wv owns jt = wv*4..+3; coupled units = B-frag k-slices {2wv,2wv+1} ->
// per-wave zbuf (12288 B = 64 units x 48 rows) aliases exactly those slices:
//   zword(r,x) = (r<24 ? wv*1536 + r*64 : 6144 + wv*1536 + (r-24)*64) + x
//   x = (jl + 4*(r&15)) & 63   (rotation swizzle, verified R9: conflicts 4x down)
// K rotation: kt = (2wv+2+i)&7 — foreign slices read by i<=5, own last; barrier
// moved inside the K-loop at i==6 (verified R10).
// Final-layer reduction: in-wave shfl_xor butterfly (sum over jgl = lanes 8
// apart) -> tiny redw buffer; kills the 14 KB red2 -> LDS 50.5 KB, 3 blocks/CU.
__global__ __launch_bounds__(256, 3)
void pinn_mfma(const float* __restrict__ X,
               const float* __restrict__ W0, const float* __restrict__ b0,
               const float* __restrict__ b1, const float* __restrict__ b2,
               const float* __restrict__ b3,
               const float* __restrict__ W4, const float* __restrict__ b4,
               const float* __restrict__ lb, const float* __restrict__ ub,
               const __bf16* __restrict__ wsw,
               float* __restrict__ out, int N)
{
    __shared__ __attribute__((aligned(16))) char  smem[49152];   // Bhi|Blo
    __shared__ __attribute__((aligned(16))) float redw[336];     // [ch*42+s*6+m][wv]
    bf16x8_a* BhiV = (bf16x8_a*)smem;             // vec idx = (kt*3+rt)*64 + lane
    bf16x8_a* BloV = (bf16x8_a*)(smem + 24576);
    f32_a*    zb   = (f32_a*)smem;                // per-wave zbuf view

    const int t    = threadIdx.x;
    const int s0   = blockIdx.x * MSAMP;
    const int wv   = t >> 6, lane = t & 63;
    const int q    = lane >> 4, c = lane & 15;    // C/D + B-frag coords
    const int jgl  = lane >> 3, m = lane & 7;     // coupling task (unit octet, sample)
    const int jg   = wv * 8 + jgl;                // global unit octet 0..31
    const int kt0  = jg >> 2, lq0 = jg & 3;       // B-frag k coords for jg
    const bf16x8 zvec = {};

    float lbv[3], cv[3];
    #pragma unroll
    for (int k = 0; k < 3; ++k) { lbv[k] = lb[k]; cv[k] = 2.0f / (ub[k] - lbv[k]); }

    // ---------------- layer 0: inputs -> first hidden states (B frags) ----------------
    {
        const int jg0 = t >> 3, m0 = t & 7;       // active if m0 < 6 (192 tasks)
        if (m0 < 6) {
            const int n = s0 + m0;
            float x0 = 0.f, x1 = 0.f, x2 = 0.f;
            if (n < N) { x0 = X[n*3+0]; x1 = X[n*3+1]; x2 = X[n*3+2]; }
            const float h0 = cv[0]*(x0 - lbv[0]) - 1.0f;
            const float h1 = cv[1]*(x1 - lbv[1]) - 1.0f;
            const float h2 = cv[2]*(x2 - lbv[2]) - 1.0f;

            float w0v[8], w1v[8], w2v[8], bv[8];
            *(f32x4*)&w0v[0] = *(const f32x4*)&W0[0*256 + jg0*8];
            *(f32x4*)&w0v[4] = *(const f32x4*)&W0[0*256 + jg0*8 + 4];
            *(f32x4*)&w1v[0] = *(const f32x4*)&W0[1*256 + jg0*8];
            *(f32x4*)&w1v[4] = *(const f32x4*)&W0[1*256 + jg0*8 + 4];
            *(f32x4*)&w2v[0] = *(const f32x4*)&W0[2*256 + jg0*8];
            *(f32x4*)&w2v[4] = *(const f32x4*)&W0[2*256 + jg0*8 + 4];
            *(f32x4*)&bv[0]  = *(const f32x4*)&b0[jg0*8];
            *(f32x4*)&bv[4]  = *(const f32x4*)&b0[jg0*8 + 4];

            float st[7][8];
            #pragma unroll
            for (int jj = 0; jj < 8; ++jj) {
                const float zH  = h0*w0v[jj] + h1*w1v[jj] + h2*w2v[jj] + bv[jj];
                const float zt0 = cv[0]*w0v[jj];
                const float zt1 = cv[1]*w1v[jj];
                const float zt2 = cv[2]*w2v[jj];
                const float h   = tanh_fast(zH);
                const float dd  = 1.0f - h*h;
                const float qq  = -2.0f * h * (zt0 + zt1 + zt2);
                st[0][jj] = h;
                st[1][jj] = dd * zt0; st[2][jj] = dd * zt1; st[3][jj] = dd * zt2;
                st[4][jj] = dd * (qq*zt0); st[5][jj] = dd * (qq*zt1); st[6][jj] = dd * (qq*zt2);
            }
            const int k0a = jg0 >> 2, l0a = jg0 & 3;
            #pragma unroll
            for (int s = 0; s < 7; ++s) {
                const int r = s*6 + m0;
                const int vid = (k0a*3 + (r>>4))*64 + l0a*16 + (r & 15);
                bf16x8 vh, vl;
                #pragma unroll
                for (int jj = 0; jj < 8; ++jj) {
                    vh[jj] = (__bf16)st[s][jj];
                    vl[jj] = (__bf16)(st[s][jj] - (float)vh[jj]);
                }
                BhiV[vid] = vh;
                BloV[vid] = vl;
            }
        }
        // zero pad rows 42..47 (r>>4==2, r&15 in 10..15): 8 kt x 4 lq x 6 = 192 vecs
        if (t < 192) {
            const int kt = t / 24, rem = t % 24, lq = rem / 6, rr = 10 + rem % 6;
            const int vid = (kt*3 + 2)*64 + lq*16 + rr;
            BhiV[vid] = zvec;
            BloV[vid] = zvec;
        }
    }
    __syncthreads();

    // ---------------- hidden layers: rotated-K GEMM + wave-local coupling ----------------
    #pragma unroll 1
    for (int l = 0; l < 3; ++l) {
        const __bf16* __restrict__ Wb = wsw + (size_t)l * 131072;
        const int ktbase = 2*wv + 2;

        f32x4 acc[4][3];   // [mtj][rt]
        #pragma unroll
        for (int a = 0; a < 4; ++a)
            #pragma unroll
            for (int b = 0; b < 3; ++b) acc[a][b] = (f32x4){0.f, 0.f, 0.f, 0.f};

        // register double-buffer: preload i=0
        bf16x8 shc[3], slc[3], whc[4], wlc[4];
        {
            const int kt = ktbase & 7;
            #pragma unroll
            for (int rt = 0; rt < 3; ++rt) {
                const int vid = (kt*3 + rt)*64 + lane;
                shc[rt] = BhiV[vid];
                slc[rt] = BloV[vid];
            }
            #pragma unroll
            for (int mtj = 0; mtj < 4; ++mtj) {
                const int jt = wv*4 + mtj;
                whc[mtj] = *(const bf16x8*)&Wb[(size_t)((kt*16 + jt)*2 + 0)*512 + lane*8];
                wlc[mtj] = *(const bf16x8*)&Wb[(size_t)((kt*16 + jt)*2 + 1)*512 + lane*8];
            }
        }

        #pragma unroll
        for (int i = 0; i < 8; ++i) {
            if (i == 6) __syncthreads();   // b1 (moved): all foreign-slice reads done
            bf16x8 shn[3], sln[3], whn[4], wln[4];
            if (i < 7) {
                const int ktn = (ktbase + i + 1) & 7;
                #pragma unroll
                for (int rt = 0; rt < 3; ++rt) {
                    const int vid = (ktn*3 + rt)*64 + lane;
                    shn[rt] = BhiV[vid];
                    sln[rt] = BloV[vid];
                }
                #pragma unroll
                for (int mtj = 0; mtj < 4; ++mtj) {
                    const int jt = wv*4 + mtj;
                    whn[mtj] = *(const bf16x8*)&Wb[(size_t)((ktn*16 + jt)*2 + 0)*512 + lane*8];
                    wln[mtj] = *(const bf16x8*)&Wb[(size_t)((ktn*16 + jt)*2 + 1)*512 + lane*8];
                }
            }
            #pragma unroll
            for (int mtj = 0; mtj < 4; ++mtj) {
                #pragma unroll
                for (int rt = 0; rt < 3; ++rt) {
                    f32x4 cc2 = acc[mtj][rt];
                    cc2 = __builtin_amdgcn_mfma_f32_16x16x32_bf16(wlc[mtj], shc[rt], cc2, 0, 0, 0);
                    cc2 = __builtin_amdgcn_mfma_f32_16x16x32_bf16(whc[mtj], slc[rt], cc2, 0, 0, 0);
                    cc2 = __builtin_amdgcn_mfma_f32_16x16x32_bf16(whc[mtj], shc[rt], cc2, 0, 0, 0);
                    acc[mtj][rt] = cc2;
                }
            }
            if (i < 7) {
                #pragma unroll
                for (int rt = 0; rt < 3; ++rt) { shc[rt] = shn[rt]; slc[rt] = sln[rt]; }
                #pragma unroll
                for (int mtj = 0; mtj < 4; ++mtj) { whc[mtj] = whn[mtj]; wlc[mtj] = wln[mtj]; }
            }
        }

        // C frags -> wave-local zbuf (own slices only)
        #pragma unroll
        for (int mtj = 0; mtj < 4; ++mtj) {
            const int jl = mtj*16 + q*4;
            #pragma unroll
            for (int rt = 0; rt < 3; ++rt) {
                const int r = rt*16 + c;
                const int base = (r < 24) ? (wv*1536 + r*64)
                                          : (6144 + wv*1536 + (r-24)*64);
                *(f32x4_a*)&zb[base + ((jl + 4*(r&15)) & 63)] = acc[mtj][rt];
            }
        }
        asm volatile("s_waitcnt lgkmcnt(0)" ::: "memory");   // stores visible to own wave

        // coupling: lane owns (jg, m); valid work only for m < 6 (others compute garbage,
        // discarded — butterfly mixes only same-m lanes, epilogue reads m<6 only)
        {
            const float* __restrict__ bb = (l == 0) ? b1 : (l == 1) ? b2 : b3;
            float bvv[8];
            *(f32x4*)&bvv[0] = *(const f32x4*)&bb[jg*8];
            *(f32x4*)&bvv[4] = *(const f32x4*)&bb[jg*8 + 4];

            float z[7][8];
            #pragma unroll
            for (int s = 0; s < 7; ++s) {
                const int r    = s*6 + m;                    // <= 43, always in range
                const int base = (r < 24) ? (wv*1536 + r*64)
                                          : (6144 + wv*1536 + (r-24)*64);
                const int rot  = 4*(r & 15);
                *(f32x4*)&z[s][0] = (f32x4)(*(const f32x4_a*)&zb[base + ((jgl*8     + rot) & 63)]);
                *(f32x4*)&z[s][4] = (f32x4)(*(const f32x4_a*)&zb[base + ((jgl*8 + 4 + rot) & 63)]);
            }
            float stt[7][8];
            #pragma unroll
            for (int jj = 0; jj < 8; ++jj) {
                const float zH  = z[0][jj] + bvv[jj];
                const float zt0 = z[1][jj], zt1 = z[2][jj], zt2 = z[3][jj];
                const float zr0 = z[4][jj], zr1 = z[5][jj], zr2 = z[6][jj];
                const float h   = tanh_fast(zH);
                const float dd  = 1.0f - h*h;
                const float qq  = -2.0f * h * (zt0 + zt1 + zt2);
                stt[0][jj] = h;
                stt[1][jj] = dd * zt0; stt[2][jj] = dd * zt1; stt[3][jj] = dd * zt2;
                stt[4][jj] = dd * (zr0 + qq*zt0);
                stt[5][jj] = dd * (zr1 + qq*zt1);
                stt[6][jj] = dd * (zr2 + qq*zt2);
            }

            if (l < 2) {
                if (m < 6) {
                    // write next-layer B-frags into wave's OWN k slices
                    #pragma unroll
                    for (int s = 0; s < 7; ++s) {
                        const int r = s*6 + m;
                        const int vid = (kt0*3 + (r>>4))*64 + lq0*16 + (r & 15);
                        bf16x8 vh, vl;
                        #pragma unroll
                        for (int jj = 0; jj < 8; ++jj) {
                            vh[jj] = (__bf16)stt[s][jj];
                            vl[jj] = (__bf16)(stt[s][jj] - (float)vh[jj]);
                        }
                        BhiV[vid] = vh;
                        BloV[vid] = vl;
                    }
                }
                // re-zero wave's own pad rows 42..47 (2 kt x 4 lq x 6 = 48 vecs/buffer)
                if (lane < 48) {
                    const int u = lane / 24, rem = lane % 24, lq = rem / 6, rr = 10 + rem % 6;
                    const int vid = ((2*wv + u)*3 + 2)*64 + lq*16 + rr;
                    BhiV[vid] = zvec;
                    BloV[vid] = zvec;
                }
                __syncthreads();      // b2: B-frags ready for next GEMM
            } else {
                // fused final layer: per-lane partials, then in-wave butterfly over jgl
                float w4r[16];
                #pragma unroll
                for (int q4 = 0; q4 < 4; ++q4)
                    *(f32x4*)&w4r[q4*4] = *(const f32x4*)&W4[jg*16 + q4*4];
                float p[2][7];
                #pragma unroll
                for (int s = 0; s < 7; ++s) {
                    float p0 = 0.f, p1 = 0.f;
                    #pragma unroll
                    for (int jj = 0; jj < 8; ++jj) {
                        p0 += stt[s][jj] * w4r[jj*2 + 0];
                        p1 += stt[s][jj] * w4r[jj*2 + 1];
                    }
                    p[0][s] = p0; p[1][s] = p1;
                }
                #pragma unroll
                for (int ch = 0; ch < 2; ++ch) {
                    #pragma unroll
                    for (int s = 0; s < 7; ++s) {
                        float v = p[ch][s];
                        v += __shfl_xor(v, 8);
                        v += __shfl_xor(v, 16);
                        v += __shfl_xor(v, 32);
                        p[ch][s] = v;            // sum over jgl, valid in every lane
                    }
                }
                if (jgl == 0 && m < 6) {
                    #pragma unroll
                    for (int ch = 0; ch < 2; ++ch)
                        #pragma unroll
                        for (int s = 0; s < 7; ++s)
                            redw[(ch*42 + s*6 + m)*4 + wv] = p[ch][s];
                }
                __syncthreads();      // redw fully written
            }
        }
    }

    // ---------------- output: 2 ch x 7 states x 6 samples = 84 tasks ----------------
    if (t < 84) {
        const f32x4 vv = *(const f32x4*)&redw[t*4];   // 4 wave partials
        const float v = vv[0] + vv[1] + vv[2] + vv[3];
        const int ch = t / 42, rem = t % 42, s = rem / 6, mm = rem % 6;
        const int n = s0 + mm;
        if (n < N) {
            const size_t N2 = (size_t)N * 2, N3 = (size_t)N * 3;
            if (s == 0)      out[(size_t)n*2 + ch] = v + b4[ch];
            else if (s <= 3) out[N2 + (size_t)ch*N3 + (size_t)n*3 + (s-1)] = v;
            else             out[N2 + 2*N3 + (size_t)ch*N3 + (size_t)n*3 + (s-4)] = v;
        }
    }
}

extern "C" void kernel_launch(void* const* d_in, const int* in_sizes, int n_in,
                              void* d_out, int out_size, void* d_ws, size_t ws_size,
                              hipStream_t stream) {
    const float* X  = (const float*)d_in[0];
    const float* W0 = (const float*)d_in[1];
    const float* b0 = (const float*)d_in[2];
    const float* W1 = (const float*)d_in[3];
    const float* b1 = (const float*)d_in[4];
    const float* W2 = (const float*)d_in[5];
    const float* b2 = (const float*)d_in[6];
    const float* W3 = (const float*)d_in[7];
    const float* b3 = (const float*)d_in[8];
    const float* W4 = (const float*)d_in[9];
    const float* b4 = (const float*)d_in[10];
    const float* lb = (const float*)d_in[11];
    const float* ub = (const float*)d_in[12];
    float* out = (float*)d_out;
    __bf16* wsw = (__bf16*)d_ws;   // needs 768 KB

    const int N = in_sizes[0] / 3;

    prep_w<<<768, 256, 0, stream>>>(W1, W2, W3, wsw);

    const int grid = (N + MSAMP - 1) / MSAMP;
    pinn_mfma<<<grid, 256, 0, stream>>>(X, W0, b0, b1, b2, b3, W4, b4, lb, ub,
                                        wsw, out, N);
}

// Round 12
// 257.212 us; speedup vs baseline: 1.3704x; 1.3704x over previous
//
#include <hip/hip_runtime.h>
#include <math.h>

typedef _Float16 f16x8 __attribute__((ext_vector_type(8)));
typedef float    f32x4 __attribute__((ext_vector_type(4)));
// may_alias views for the unioned LDS region (state-frags <-> per-wave zbuf)
typedef f16x8 f16x8_a __attribute__((may_alias));
typedef f32x4 f32x4_a __attribute__((may_alias));
typedef float f32_a   __attribute__((may_alias));

#define MSAMP 8       // samples per block; state-rows: r = s*8 + m, r 56..63 pad

__device__ __forceinline__ float tanh_fast(float x) {
    // 1 - 2/(exp(2x)+1); ~1e-6 abs error (verified R7..R11: absmax unchanged)
    const float e = __expf(2.0f * x);
    return 1.0f - 2.0f * __builtin_amdgcn_rcpf(e + 1.0f);
}

// W swizzle, SINGLE fp16 (2-term scheme: states carry the split, W doesn't):
//   off(l,kt,jt,lane,jj) = ((l*8+kt)*16+jt)*512 + lane*8 + jj ; per-l stride 65536
// A-fragments of W^T: lane holds A[j = jt*16+(lane&15)][k = kt*32+(lane>>4)*8+jj]
__global__ void prep_w(const float* __restrict__ W1, const float* __restrict__ W2,
                       const float* __restrict__ W3, _Float16* __restrict__ wsw) {
    const int tid = blockIdx.x * 256 + threadIdx.x;      // 3*8*16*64*8 = 196608
    if (tid >= 3 * 8 * 16 * 64 * 8) return;
    const int j    = tid & 7;
    const int lane = (tid >> 3) & 63;
    const int nt   = (tid >> 9) & 15;
    const int kt   = (tid >> 13) & 7;
    const int l    = tid >> 16;
    const float* W = (l == 0) ? W1 : (l == 1) ? W2 : W3;
    const int k = kt * 32 + (lane >> 4) * 8 + j;
    const int n = nt * 16 + (lane & 15);
    wsw[((size_t)((l * 8 + kt) * 16 + nt)) * 512 + lane * 8 + j] = (_Float16)W[k * 256 + n];
}

// TRANSPOSED GEMM (R10 geometry, fp16): D[j][r] = sum_k W^T[j][k]*S^T[k][r].
// State B-frags: Bhi (32KB, fp16 hi) | Blo (32KB, fp16 residual ~22 bits total),
// vec idx = (kt*4 + rt)*64 + lane. W single fp16 -> 2 MFMAs per (kt,mtj,rt):
//   acc = mfma_f16(wh, sl, acc); acc = mfma_f16(wh, sh, acc);
// Wave wv owns jt = wv*4..+3; coupled units = B-frag k-slices {2wv,2wv+1} ->
// per-wave zbuf (16KB) aliases exactly those slices (hi: r<32, lo: r>=32):
//   zword(r,jl) = wv*2048 + (r>>5)*8192 + (r&31)*64 + ((jl + 4*(r&15)) & 63)
// K rotation kt=(2wv+2+i)&7, barrier moved to i==6 (verified R10). Butterfly
// epilogue over jgl via shfl_xor (verified R11) -> tiny redw, no red2.
__global__ __launch_bounds__(256, 2)
void pinn_mfma(const float* __restrict__ X,
               const float* __restrict__ W0, const float* __restrict__ b0,
               const float* __restrict__ b1, const float* __restrict__ b2,
               const float* __restrict__ b3,
               const float* __restrict__ W4, const float* __restrict__ b4,
               const float* __restrict__ lb, const float* __restrict__ ub,
               const _Float16* __restrict__ wsw,
               float* __restrict__ out, int N)
{
    __shared__ __attribute__((aligned(16))) char  smem[65536];   // Bhi|Blo
    __shared__ __attribute__((aligned(16))) float redw[448];     // [ch*56+s*8+m][wv]
    f16x8_a* BhiV = (f16x8_a*)smem;               // vec idx = (kt*4+rt)*64 + lane
    f16x8_a* BloV = (f16x8_a*)(smem + 32768);
    f32_a*   zb   = (f32_a*)smem;                 // per-wave zbuf view

    const int t    = threadIdx.x;
    const int s0   = blockIdx.x * MSAMP;
    const int wv   = t >> 6, lane = t & 63;
    const int q    = lane >> 4, c = lane & 15;    // C/D + B-frag coords
    const int jgl  = lane >> 3, m = lane & 7;     // coupling task (unit octet, sample)
    const int jg   = wv * 8 + jgl;                // global unit octet 0..31
    const int kt0  = jg >> 2, lq0 = jg & 3;       // B-frag k coords for jg

    // prologue pad-zero mapping (all 8 kt, by 256 threads): zero r=56..63
    const int vidz0 = ((t >> 5) * 4 + 3) * 64 + ((t >> 3) & 3) * 16 + 8 + (t & 7);
    // per-wave pad-zero mapping (wave's own 2 kt slices, by 64 lanes)
    const int vidzw = (((wv * 2 + (lane >> 5)) * 4 + 3) * 64) + (((lane >> 3) & 3) * 16) + 8 + (lane & 7);
    const f16x8 zvec = {};

    float lbv[3], cv[3];
    #pragma unroll
    for (int k = 0; k < 3; ++k) { lbv[k] = lb[k]; cv[k] = 2.0f / (ub[k] - lbv[k]); }

    // ---------------- layer 0: inputs -> first hidden states (B frags) ----------------
    {
        const int jg0 = t >> 3, m0 = t & 7;       // prologue task mapping (global)
        const int n = s0 + m0;
        float x0 = 0.f, x1 = 0.f, x2 = 0.f;
        if (n < N) { x0 = X[n*3+0]; x1 = X[n*3+1]; x2 = X[n*3+2]; }
        const float h0 = cv[0]*(x0 - lbv[0]) - 1.0f;
        const float h1 = cv[1]*(x1 - lbv[1]) - 1.0f;
        const float h2 = cv[2]*(x2 - lbv[2]) - 1.0f;

        float w0v[8], w1v[8], w2v[8], bv[8];
        *(f32x4*)&w0v[0] = *(const f32x4*)&W0[0*256 + jg0*8];
        *(f32x4*)&w0v[4] = *(const f32x4*)&W0[0*256 + jg0*8 + 4];
        *(f32x4*)&w1v[0] = *(const f32x4*)&W0[1*256 + jg0*8];
        *(f32x4*)&w1v[4] = *(const f32x4*)&W0[1*256 + jg0*8 + 4];
        *(f32x4*)&w2v[0] = *(const f32x4*)&W0[2*256 + jg0*8];
        *(f32x4*)&w2v[4] = *(const f32x4*)&W0[2*256 + jg0*8 + 4];
        *(f32x4*)&bv[0]  = *(const f32x4*)&b0[jg0*8];
        *(f32x4*)&bv[4]  = *(const f32x4*)&b0[jg0*8 + 4];

        float st[7][8];
        #pragma unroll
        for (int jj = 0; jj < 8; ++jj) {
            const float zH  = h0*w0v[jj] + h1*w1v[jj] + h2*w2v[jj] + bv[jj];
            const float zt0 = cv[0]*w0v[jj];
            const float zt1 = cv[1]*w1v[jj];
            const float zt2 = cv[2]*w2v[jj];
            const float h   = tanh_fast(zH);
            const float dd  = 1.0f - h*h;
            const float qq  = -2.0f * h * (zt0 + zt1 + zt2);
            st[0][jj] = h;
            st[1][jj] = dd * zt0; st[2][jj] = dd * zt1; st[3][jj] = dd * zt2;
            st[4][jj] = dd * (qq*zt0); st[5][jj] = dd * (qq*zt1); st[6][jj] = dd * (qq*zt2);
        }
        const int k0a = jg0 >> 2, l0a = jg0 & 3;
        #pragma unroll
        for (int s = 0; s < 7; ++s) {
            const int r = s*8 + m0;
            const int vid = (k0a*4 + (r>>4))*64 + l0a*16 + (r & 15);
            f16x8 vh, vl;
            #pragma unroll
            for (int jj = 0; jj < 8; ++jj) {
                vh[jj] = (_Float16)st[s][jj];
                vl[jj] = (_Float16)(st[s][jj] - (float)vh[jj]);
            }
            BhiV[vid] = vh;
            BloV[vid] = vl;
        }
        BhiV[vidz0] = zvec;     // zero pad rows r = 56..63
        BloV[vidz0] = zvec;
    }
    __syncthreads();

    // ---------------- hidden layers: rotated-K GEMM + wave-local coupling ----------------
    #pragma unroll 1
    for (int l = 0; l < 3; ++l) {
        const _Float16* __restrict__ Wb = wsw + (size_t)l * 65536;
        const int ktbase = 2*wv + 2;

        f32x4 acc[4][4];   // [mtj][rt]
        #pragma unroll
        for (int a = 0; a < 4; ++a)
            #pragma unroll
            for (int b = 0; b < 4; ++b) acc[a][b] = (f32x4){0.f, 0.f, 0.f, 0.f};

        // register double-buffer: preload i=0
        f16x8 shc[4], slc[4], whc[4];
        {
            const int kt = ktbase & 7;
            #pragma unroll
            for (int rt = 0; rt < 4; ++rt) {
                const int vid = (kt*4 + rt)*64 + lane;
                shc[rt] = BhiV[vid];
                slc[rt] = BloV[vid];
            }
            #pragma unroll
            for (int mtj = 0; mtj < 4; ++mtj)
                whc[mtj] = *(const f16x8*)&Wb[(size_t)(kt*16 + wv*4 + mtj)*512 + lane*8];
        }

        #pragma unroll
        for (int i = 0; i < 8; ++i) {
            if (i == 6) __syncthreads();   // b1 (moved): all foreign-slice reads done
            f16x8 shn[4], sln[4], whn[4];
            if (i < 7) {
                const int ktn = (ktbase + i + 1) & 7;
                #pragma unroll
                for (int rt = 0; rt < 4; ++rt) {
                    const int vid = (ktn*4 + rt)*64 + lane;
                    shn[rt] = BhiV[vid];
                    sln[rt] = BloV[vid];
                }
                #pragma unroll
                for (int mtj = 0; mtj < 4; ++mtj)
                    whn[mtj] = *(const f16x8*)&Wb[(size_t)(ktn*16 + wv*4 + mtj)*512 + lane*8];
            }
            #pragma unroll
            for (int mtj = 0; mtj < 4; ++mtj) {
                #pragma unroll
                for (int rt = 0; rt < 4; ++rt) {
                    f32x4 cc2 = acc[mtj][rt];
                    cc2 = __builtin_amdgcn_mfma_f32_16x16x32_f16(whc[mtj], slc[rt], cc2, 0, 0, 0);
                    cc2 = __builtin_amdgcn_mfma_f32_16x16x32_f16(whc[mtj], shc[rt], cc2, 0, 0, 0);
                    acc[mtj][rt] = cc2;
                }
            }
            if (i < 7) {
                #pragma unroll
                for (int rt = 0; rt < 4; ++rt) { shc[rt] = shn[rt]; slc[rt] = sln[rt]; }
                #pragma unroll
                for (int mtj = 0; mtj < 4; ++mtj) whc[mtj] = whn[mtj];
            }
        }

        // C frags -> wave-local zbuf (own slices only), vector b128 stores
        #pragma unroll
        for (int mtj = 0; mtj < 4; ++mtj) {
            const int jl = mtj*16 + q*4;
            #pragma unroll
            for (int rt = 0; rt < 4; ++rt) {
                const int r = rt*16 + c;
                const int word = wv*2048 + (r>>5)*8192 + (r&31)*64 + ((jl + 4*(r&15)) & 63);
                *(f32x4_a*)&zb[word] = acc[mtj][rt];
            }
        }
        asm volatile("s_waitcnt lgkmcnt(0)" ::: "memory");   // stores visible to own wave

        // coupling: lane owns (jg = wv*8+jgl, sample m)
        {
            const float* __restrict__ bb = (l == 0) ? b1 : (l == 1) ? b2 : b3;
            float bvv[8];
            *(f32x4*)&bvv[0] = *(const f32x4*)&bb[jg*8];
            *(f32x4*)&bvv[4] = *(const f32x4*)&bb[jg*8 + 4];

            float z[7][8];
            #pragma unroll
            for (int s = 0; s < 7; ++s) {
                const int r    = s*8 + m;
                const int base = wv*2048 + (r>>5)*8192 + (r&31)*64;
                const int rot  = 4*(r & 15);
                *(f32x4*)&z[s][0] = (f32x4)(*(const f32x4_a*)&zb[base + ((jgl*8     + rot) & 63)]);
                *(f32x4*)&z[s][4] = (f32x4)(*(const f32x4_a*)&zb[base + ((jgl*8 + 4 + rot) & 63)]);
            }
            float stt[7][8];
            #pragma unroll
            for (int jj = 0; jj < 8; ++jj) {
                const float zH  = z[0][jj] + bvv[jj];
                const float zt0 = z[1][jj], zt1 = z[2][jj], zt2 = z[3][jj];
                const float zr0 = z[4][jj], zr1 = z[5][jj], zr2 = z[6][jj];
                const float h   = tanh_fast(zH);
                const float dd  = 1.0f - h*h;
                const float qq  = -2.0f * h * (zt0 + zt1 + zt2);
                stt[0][jj] = h;
                stt[1][jj] = dd * zt0; stt[2][jj] = dd * zt1; stt[3][jj] = dd * zt2;
                stt[4][jj] = dd * (zr0 + qq*zt0);
                stt[5][jj] = dd * (zr1 + qq*zt1);
                stt[6][jj] = dd * (zr2 + qq*zt2);
            }

            if (l < 2) {
                // write next-layer B-frags into wave's OWN k slices
                #pragma unroll
                for (int s = 0; s < 7; ++s) {
                    const int r = s*8 + m;
                    const int vid = (kt0*4 + (r>>4))*64 + lq0*16 + (r & 15);
                    f16x8 vh, vl;
                    #pragma unroll
                    for (int jj = 0; jj < 8; ++jj) {
                        vh[jj] = (_Float16)stt[s][jj];
                        vl[jj] = (_Float16)(stt[s][jj] - (float)vh[jj]);
                    }
                    BhiV[vid] = vh;
                    BloV[vid] = vl;
                }
                BhiV[vidzw] = zvec;   // re-zero wave's pad rows r=56..63
                BloV[vidzw] = zvec;
                __syncthreads();      // b2: B-frags ready for next GEMM
            } else {
                // fused final layer: per-lane partials + in-wave butterfly over jgl
                float w4r[16];
                #pragma unroll
                for (int q4 = 0; q4 < 4; ++q4)
                    *(f32x4*)&w4r[q4*4] = *(const f32x4*)&W4[jg*16 + q4*4];
                float p[2][7];
                #pragma unroll
                for (int s = 0; s < 7; ++s) {
                    float p0 = 0.f, p1 = 0.f;
                    #pragma unroll
                    for (int jj = 0; jj < 8; ++jj) {
                        p0 += stt[s][jj] * w4r[jj*2 + 0];
                        p1 += stt[s][jj] * w4r[jj*2 + 1];
                    }
                    p[0][s] = p0; p[1][s] = p1;
                }
                #pragma unroll
                for (int ch = 0; ch < 2; ++ch) {
                    #pragma unroll
                    for (int s = 0; s < 7; ++s) {
                        float v = p[ch][s];
                        v += __shfl_xor(v, 8);
                        v += __shfl_xor(v, 16);
                        v += __shfl_xor(v, 32);
                        p[ch][s] = v;            // sum over jgl, valid in every lane
                    }
                }
                if (jgl == 0) {
                    #pragma unroll
                    for (int ch = 0; ch < 2; ++ch)
                        #pragma unroll
                        for (int s = 0; s < 7; ++s)
                            redw[(ch*56 + s*8 + m)*4 + wv] = p[ch][s];
                }
                __syncthreads();      // redw fully written
            }
        }
    }

    // ---------------- output: 2 ch x 7 states x 8 samples = 112 tasks ----------------
    if (t < 112) {
        const f32x4 vv = *(const f32x4*)&redw[t*4];   // 4 wave partials
        const float v = vv[0] + vv[1] + vv[2] + vv[3];
        const int ch = t / 56, rem = t % 56, s = rem >> 3, mm = rem & 7;
        const int n = s0 + mm;
        if (n < N) {
            const size_t N2 = (size_t)N * 2, N3 = (size_t)N * 3;
            if (s == 0)      out[(size_t)n*2 + ch] = v + b4[ch];
            else if (s <= 3) out[N2 + (size_t)ch*N3 + (size_t)n*3 + (s-1)] = v;
            else             out[N2 + 2*N3 + (size_t)ch*N3 + (size_t)n*3 + (s-4)] = v;
        }
    }
}

extern "C" void kernel_launch(void* const* d_in, const int* in_sizes, int n_in,
                              void* d_out, int out_size, void* d_ws, size_t ws_size,
                              hipStream_t stream) {
    const float* X  = (const float*)d_in[0];
    const float* W0 = (const float*)d_in[1];
    const float* b0 = (const float*)d_in[2];
    const float* W1 = (const float*)d_in[3];
    const float* b1 = (const float*)d_in[4];
    const float* W2 = (const float*)d_in[5];
    const float* b2 = (const float*)d_in[6];
    const float* W3 = (const float*)d_in[7];
    const float* b3 = (const float*)d_in[8];
    const float* W4 = (const float*)d_in[9];
    const float* b4 = (const float*)d_in[10];
    const float* lb = (const float*)d_in[11];
    const float* ub = (const float*)d_in[12];
    float* out = (float*)d_out;
    _Float16* wsw = (_Float16*)d_ws;   // needs 384 KB

    const int N = in_sizes[0] / 3;

    prep_w<<<768, 256, 0, stream>>>(W1, W2, W3, wsw);

    const int grid = (N + MSAMP - 1) / MSAMP;
    pinn_mfma<<<grid, 256, 0, stream>>>(X, W0, b0, b1, b2, b3, W4, b4, lb, ub,
                                        wsw, out, N);
}